// Round 5
// baseline (197.603 us; speedup 1.0000x reference)
//
#include <hip/hip_runtime.h>

// PrototypeClassifier: B=262144, P=512, D=40, O=256
// xmat[i,p] = dist[i] (scalar broadcast), out[i,o] = dist[i]*Wsum[o] + b[o]
// dist[i] = sqrt(512*||x_i||^2 - 2*x_i.proto_sum + ||proto||_F^2)

#define B_ROWS 262144
#define P_N 512
#define D_N 40
#define O_N 256
#define GRID_T (2048 * 256)  // stream kernel total threads

typedef float f4 __attribute__((ext_vector_type(4)));

// ws layout (floats): [0,40) proto_sum, [40,296) Wsum, [296,336) per-dim proto
// sum-of-squares, [512, 512+B) dist (split path only)

__global__ __launch_bounds__(256) void pre_kernel(const float* __restrict__ proto,
                                                  const float* __restrict__ W,
                                                  float* __restrict__ ws) {
    __shared__ float sm[4];
    const int t = threadIdx.x;
    const int blk = blockIdx.x;
    const int lane = t & 63, w = t >> 6;
    if (blk < D_N) {
        float s = 0.f, sq = 0.f;
        for (int p = t; p < P_N; p += 256) {
            float v = proto[p * D_N + blk];
            s += v;
            sq += v * v;
        }
        #pragma unroll
        for (int off = 32; off; off >>= 1) {
            s += __shfl_xor(s, off);
            sq += __shfl_xor(sq, off);
        }
        if (lane == 0) sm[w] = s;
        __syncthreads();
        if (t == 0) ws[blk] = sm[0] + sm[1] + sm[2] + sm[3];
        __syncthreads();
        if (lane == 0) sm[w] = sq;
        __syncthreads();
        if (t == 0) ws[296 + blk] = sm[0] + sm[1] + sm[2] + sm[3];
    } else {
        const int o = blk - D_N;
        float s = 0.f;
        for (int p = t; p < P_N; p += 256) s += W[(long)o * P_N + p];
        #pragma unroll
        for (int off = 32; off; off >>= 1) s += __shfl_xor(s, off);
        if (lane == 0) sm[w] = s;
        __syncthreads();
        if (t == 0) ws[40 + o] = sm[0] + sm[1] + sm[2] + sm[3];
    }
}

// 256 rows/block. Coalesced float4 staging of x into LDS (pad 41 -> odd
// stride), then thread t computes dist for row t from LDS.
__global__ __launch_bounds__(256) void dist_kernel(const float* __restrict__ x,
                                                   const float* __restrict__ ws,
                                                   float* __restrict__ dist) {
    __shared__ float sx[256 * 41];  // 41 KB
    const int t = threadIdx.x;
    const long rbase = (long)blockIdx.x * 256;
    const float4* __restrict__ xg = reinterpret_cast<const float4*>(x + rbase * D_N);
    #pragma unroll
    for (int k = 0; k < 10; ++k) {
        const int g = t + 256 * k;      // 2560 float4s, unit-stride across block
        const float4 v = xg[g];
        const int r = g / 10;           // each float4 lies within one row (40%4==0)
        const int c = g - r * 10;
        float* p = &sx[r * 41 + c * 4];
        p[0] = v.x; p[1] = v.y; p[2] = v.z; p[3] = v.w;
    }
    __syncthreads();
    const float* __restrict__ ps = ws;        // proto_sum
    const float* __restrict__ pq = ws + 296;  // per-dim proto sq
    const float* row = &sx[t * 41];
    float sumsq = 0.f, dot = 0.f, psq = 0.f;
    #pragma unroll
    for (int k = 0; k < D_N; ++k) {
        const float v = row[k];
        sumsq = fmaf(v, v, sumsq);
        dot   = fmaf(v, ps[k], dot);
        psq  += pq[k];
    }
    dist[rbase + t] = sqrtf(fmaf(512.f, sumsq, fmaf(-2.f, dot, psq)));
}

// Grid-stride SWEEP streamer (fill-kernel pattern): the whole grid advances as
// one contiguous 8 MB front over each flat output. row index is wave-uniform
// (front stride 524288 and wave span 64 both align to row granularity), so
// dist[row] is a readfirstlane + scalar load -> vector pipe issues only stores.
__global__ __launch_bounds__(256) void stream_kernel(const float* __restrict__ b,
                                                     const float* __restrict__ ws,
                                                     const float* __restrict__ dist,
                                                     float* __restrict__ xmat,
                                                     float* __restrict__ outp) {
    const int t = threadIdx.x;
    const int g = blockIdx.x * 256 + t;
    const float4 wv = reinterpret_cast<const float4*>(ws + 40)[t & 63];
    const float4 bv = reinterpret_cast<const float4*>(b)[t & 63];

    // phase 1: xmat, 33,554,432 float4 flat, 64 front steps
    f4* __restrict__ xm = reinterpret_cast<f4*>(xmat);
    #pragma unroll 8
    for (int i = 0; i < 64; ++i) {
        const int j = i * GRID_T + g;
        const int row = __builtin_amdgcn_readfirstlane(j >> 7);
        const float d = dist[row];
        f4 val = {d, d, d, d};
        xm[j] = val;
    }

    // phase 2: out, 16,777,216 float4 flat, 32 front steps
    f4* __restrict__ om = reinterpret_cast<f4*>(outp);
    #pragma unroll 8
    for (int i = 0; i < 32; ++i) {
        const int j = i * GRID_T + g;
        const int row = __builtin_amdgcn_readfirstlane(j >> 6);
        const float d = dist[row];
        f4 val = {fmaf(d, wv.x, bv.x), fmaf(d, wv.y, bv.y),
                  fmaf(d, wv.z, bv.z), fmaf(d, wv.w, bv.w)};
        om[j] = val;
    }
}

// fallback: fused single-pass (used only if ws too small for dist array)
__global__ __launch_bounds__(256) void fused_kernel(const float* __restrict__ x,
                                                    const float* __restrict__ b,
                                                    const float* __restrict__ ws,
                                                    float* __restrict__ xmat,
                                                    float* __restrict__ outp) {
    __shared__ float sdist[256];
    const int t = threadIdx.x;
    const long base = (long)blockIdx.x * 256;
    const float4* __restrict__ xr  = reinterpret_cast<const float4*>(x + (base + t) * D_N);
    const float4* __restrict__ ps4 = reinterpret_cast<const float4*>(ws);
    const float4* __restrict__ pq4 = reinterpret_cast<const float4*>(ws + 296);
    float sumsq = 0.f, dot = 0.f, psq = 0.f;
    #pragma unroll
    for (int k = 0; k < D_N / 4; ++k) {
        const float4 v = xr[k];
        const float4 p = ps4[k];
        const float4 q = pq4[k];
        sumsq = fmaf(v.x, v.x, fmaf(v.y, v.y, fmaf(v.z, v.z, fmaf(v.w, v.w, sumsq))));
        dot   = fmaf(v.x, p.x, fmaf(v.y, p.y, fmaf(v.z, p.z, fmaf(v.w, p.w, dot))));
        psq  += q.x + q.y + q.z + q.w;
    }
    sdist[t] = sqrtf(fmaf(512.f, sumsq, fmaf(-2.f, dot, psq)));
    __syncthreads();

    float4* __restrict__ xm = reinterpret_cast<float4*>(xmat + base * P_N);
    #pragma unroll 8
    for (int i = 0; i < 128; ++i) {
        const int j = i * 256 + t;
        const float d = sdist[j >> 7];
        xm[j] = make_float4(d, d, d, d);
    }
    const float4 wv = reinterpret_cast<const float4*>(ws + 40)[t & 63];
    const float4 bv = reinterpret_cast<const float4*>(b)[t & 63];
    float4* __restrict__ om = reinterpret_cast<float4*>(outp + base * O_N);
    #pragma unroll 8
    for (int i = 0; i < 64; ++i) {
        const int j = i * 256 + t;
        const float d = sdist[j >> 6];
        om[j] = make_float4(fmaf(d, wv.x, bv.x), fmaf(d, wv.y, bv.y),
                            fmaf(d, wv.z, bv.z), fmaf(d, wv.w, bv.w));
    }
}

extern "C" void kernel_launch(void* const* d_in, const int* in_sizes, int n_in,
                              void* d_out, int out_size, void* d_ws, size_t ws_size,
                              hipStream_t stream) {
    const float* inp   = (const float*)d_in[0];
    const float* proto = (const float*)d_in[1];
    const float* W     = (const float*)d_in[2];
    const float* b     = (const float*)d_in[3];
    float* ws   = (float*)d_ws;
    float* xmat = (float*)d_out;
    float* outp = xmat + (long)B_ROWS * P_N;

    hipLaunchKernelGGL(pre_kernel, dim3(296), dim3(256), 0, stream, proto, W, ws);

    if (ws_size >= (size_t)(512 + B_ROWS + 64) * sizeof(float)) {
        float* dist = ws + 512;
        hipLaunchKernelGGL(dist_kernel, dim3(B_ROWS / 256), dim3(256), 0, stream,
                           inp, ws, dist);
        hipLaunchKernelGGL(stream_kernel, dim3(GRID_T / 256), dim3(256), 0, stream,
                           b, ws, dist, xmat, outp);
    } else {
        hipLaunchKernelGGL(fused_kernel, dim3(B_ROWS / 256), dim3(256), 0, stream,
                           inp, b, ws, xmat, outp);
    }
}

// Round 6
// 160.684 us; speedup vs baseline: 1.2298x; 1.2298x over previous
//
#include <hip/hip_runtime.h>

// PrototypeClassifier: B=262144, P=512, D=40, O=256
// xmat[i,p] = dist[i] (scalar broadcast), out[i,o] = dist[i]*Wsum[o] + b[o]
// dist[i] = sqrt(512*||x_i||^2 - 2*x_i.proto_sum + ||proto||_F^2)

#define B_ROWS 262144
#define P_N 512
#define D_N 40
#define O_N 256
#define XM_F4 (B_ROWS * P_N / 4)   // 33,554,432 float4
#define XM_BLKS (XM_F4 / 256)      // 131,072 blocks
#define OM_F4 (B_ROWS * O_N / 4)   // 16,777,216 float4
#define OM_BLKS (OM_F4 / 256)      // 65,536 blocks

typedef float f4 __attribute__((ext_vector_type(4)));

// ws layout (floats): [0,40) proto_sum, [40,296) Wsum, [296,336) per-dim proto
// sum-of-squares, [512, 512+B) dist (split path only)

__global__ __launch_bounds__(256) void pre_kernel(const float* __restrict__ proto,
                                                  const float* __restrict__ W,
                                                  float* __restrict__ ws) {
    __shared__ float sm[4];
    const int t = threadIdx.x;
    const int blk = blockIdx.x;
    const int lane = t & 63, w = t >> 6;
    if (blk < D_N) {
        float s = 0.f, sq = 0.f;
        for (int p = t; p < P_N; p += 256) {
            float v = proto[p * D_N + blk];
            s += v;
            sq += v * v;
        }
        #pragma unroll
        for (int off = 32; off; off >>= 1) {
            s += __shfl_xor(s, off);
            sq += __shfl_xor(sq, off);
        }
        if (lane == 0) sm[w] = s;
        __syncthreads();
        if (t == 0) ws[blk] = sm[0] + sm[1] + sm[2] + sm[3];
        __syncthreads();
        if (lane == 0) sm[w] = sq;
        __syncthreads();
        if (t == 0) ws[296 + blk] = sm[0] + sm[1] + sm[2] + sm[3];
    } else {
        const int o = blk - D_N;
        float s = 0.f;
        for (int p = t; p < P_N; p += 256) s += W[(long)o * P_N + p];
        #pragma unroll
        for (int off = 32; off; off >>= 1) s += __shfl_xor(s, off);
        if (lane == 0) sm[w] = s;
        __syncthreads();
        if (t == 0) ws[40 + o] = sm[0] + sm[1] + sm[2] + sm[3];
    }
}

// one thread = one row's dist (R3 version — best-measured config)
__global__ __launch_bounds__(256) void dist_kernel(const float* __restrict__ x,
                                                   const float* __restrict__ ws,
                                                   float* __restrict__ dist) {
    const long i = (long)blockIdx.x * 256 + threadIdx.x;
    const float4* __restrict__ xr  = reinterpret_cast<const float4*>(x + i * D_N);
    const float4* __restrict__ ps4 = reinterpret_cast<const float4*>(ws);
    const float4* __restrict__ pq4 = reinterpret_cast<const float4*>(ws + 296);
    float sumsq = 0.f, dot = 0.f, psq = 0.f;
    #pragma unroll
    for (int k = 0; k < D_N / 4; ++k) {
        const float4 v = xr[k];
        const float4 p = ps4[k];
        const float4 q = pq4[k];
        sumsq = fmaf(v.x, v.x, fmaf(v.y, v.y, fmaf(v.z, v.z, fmaf(v.w, v.w, sumsq))));
        dot   = fmaf(v.x, p.x, fmaf(v.y, p.y, fmaf(v.z, p.z, fmaf(v.w, p.w, dot))));
        psq  += q.x + q.y + q.z + q.w;
    }
    dist[i] = sqrtf(fmaf(512.f, sumsq, fmaf(-2.f, dot, psq)));
}

// Fill-shaped streamer: one float4 store per thread, maximal grid, no LDS,
// no loop. Block-uniform branch selects xmat vs out region. dist[] (1 MB)
// and wv/bv (1 KB each) are L1/L2-resident.
__global__ __launch_bounds__(256) void fill_kernel(const float* __restrict__ b,
                                                   const float* __restrict__ ws,
                                                   const float* __restrict__ dist,
                                                   f4* __restrict__ xm,
                                                   f4* __restrict__ om) {
    const int t = threadIdx.x;
    const unsigned bid = blockIdx.x;
    if (bid < (unsigned)XM_BLKS) {
        const unsigned j = bid * 256u + t;           // float4 index in xmat
        const float d = dist[j >> 7];                // 1-2 lines per wave, cached
        f4 v = {d, d, d, d};
        xm[j] = v;
    } else {
        const unsigned j = (bid - XM_BLKS) * 256u + t;  // float4 index in out
        const float d = dist[j >> 6];
        const float4 wv = reinterpret_cast<const float4*>(ws + 40)[t & 63];
        const float4 bv = reinterpret_cast<const float4*>(b)[t & 63];
        f4 v = {fmaf(d, wv.x, bv.x), fmaf(d, wv.y, bv.y),
                fmaf(d, wv.z, bv.z), fmaf(d, wv.w, bv.w)};
        om[j] = v;
    }
}

// fallback: fused single-pass (used only if ws too small for dist array)
__global__ __launch_bounds__(256) void fused_kernel(const float* __restrict__ x,
                                                    const float* __restrict__ b,
                                                    const float* __restrict__ ws,
                                                    float* __restrict__ xmat,
                                                    float* __restrict__ outp) {
    __shared__ float sdist[256];
    const int t = threadIdx.x;
    const long base = (long)blockIdx.x * 256;
    const float4* __restrict__ xr  = reinterpret_cast<const float4*>(x + (base + t) * D_N);
    const float4* __restrict__ ps4 = reinterpret_cast<const float4*>(ws);
    const float4* __restrict__ pq4 = reinterpret_cast<const float4*>(ws + 296);
    float sumsq = 0.f, dot = 0.f, psq = 0.f;
    #pragma unroll
    for (int k = 0; k < D_N / 4; ++k) {
        const float4 v = xr[k];
        const float4 p = ps4[k];
        const float4 q = pq4[k];
        sumsq = fmaf(v.x, v.x, fmaf(v.y, v.y, fmaf(v.z, v.z, fmaf(v.w, v.w, sumsq))));
        dot   = fmaf(v.x, p.x, fmaf(v.y, p.y, fmaf(v.z, p.z, fmaf(v.w, p.w, dot))));
        psq  += q.x + q.y + q.z + q.w;
    }
    sdist[t] = sqrtf(fmaf(512.f, sumsq, fmaf(-2.f, dot, psq)));
    __syncthreads();

    float4* __restrict__ xm = reinterpret_cast<float4*>(xmat + base * P_N);
    #pragma unroll 8
    for (int i = 0; i < 128; ++i) {
        const int j = i * 256 + t;
        const float d = sdist[j >> 7];
        xm[j] = make_float4(d, d, d, d);
    }
    const float4 wv = reinterpret_cast<const float4*>(ws + 40)[t & 63];
    const float4 bv = reinterpret_cast<const float4*>(b)[t & 63];
    float4* __restrict__ om = reinterpret_cast<float4*>(outp + base * O_N);
    #pragma unroll 8
    for (int i = 0; i < 64; ++i) {
        const int j = i * 256 + t;
        const float d = sdist[j >> 6];
        om[j] = make_float4(fmaf(d, wv.x, bv.x), fmaf(d, wv.y, bv.y),
                            fmaf(d, wv.z, bv.z), fmaf(d, wv.w, bv.w));
    }
}

extern "C" void kernel_launch(void* const* d_in, const int* in_sizes, int n_in,
                              void* d_out, int out_size, void* d_ws, size_t ws_size,
                              hipStream_t stream) {
    const float* inp   = (const float*)d_in[0];
    const float* proto = (const float*)d_in[1];
    const float* W     = (const float*)d_in[2];
    const float* b     = (const float*)d_in[3];
    float* ws   = (float*)d_ws;
    float* xmat = (float*)d_out;
    float* outp = xmat + (long)B_ROWS * P_N;

    hipLaunchKernelGGL(pre_kernel, dim3(296), dim3(256), 0, stream, proto, W, ws);

    if (ws_size >= (size_t)(512 + B_ROWS + 64) * sizeof(float)) {
        float* dist = ws + 512;
        hipLaunchKernelGGL(dist_kernel, dim3(B_ROWS / 256), dim3(256), 0, stream,
                           inp, ws, dist);
        hipLaunchKernelGGL(fill_kernel, dim3(XM_BLKS + OM_BLKS), dim3(256), 0, stream,
                           b, ws, dist, (f4*)xmat, (f4*)outp);
    } else {
        hipLaunchKernelGGL(fused_kernel, dim3(B_ROWS / 256), dim3(256), 0, stream,
                           inp, b, ws, xmat, outp);
    }
}

// Round 7
// 149.846 us; speedup vs baseline: 1.3187x; 1.0723x over previous
//
#include <hip/hip_runtime.h>

// PrototypeClassifier: B=262144, P=512, D=40, O=256
// xmat[i,p] = dist[i] (scalar broadcast), out[i,o] = dist[i]*Wsum[o] + b[o]
// dist[i] = sqrt(512*||x_i||^2 - 2*x_i.proto_sum + ||proto||_F^2)

#define B_ROWS 262144
#define P_N 512
#define D_N 40
#define O_N 256
#define XM_F4 (B_ROWS * P_N / 4)   // 33,554,432 float4
#define XM_BLKS (XM_F4 / 256)      // 131,072 blocks
#define OM_F4 (B_ROWS * O_N / 4)   // 16,777,216 float4
#define OM_BLKS (OM_F4 / 256)      // 65,536 blocks

typedef float f4 __attribute__((ext_vector_type(4)));

// ws layout (floats): [0,40) proto_sum, [40,296) Wsum, [296,336) per-dim proto
// sum-of-squares, [512, 512+B) dist (split path only)

__global__ __launch_bounds__(256) void pre_kernel(const float* __restrict__ proto,
                                                  const float* __restrict__ W,
                                                  float* __restrict__ ws) {
    __shared__ float sm[4];
    const int t = threadIdx.x;
    const int blk = blockIdx.x;
    const int lane = t & 63, w = t >> 6;
    if (blk < D_N) {
        float s = 0.f, sq = 0.f;
        for (int p = t; p < P_N; p += 256) {
            float v = proto[p * D_N + blk];
            s += v;
            sq += v * v;
        }
        #pragma unroll
        for (int off = 32; off; off >>= 1) {
            s += __shfl_xor(s, off);
            sq += __shfl_xor(sq, off);
        }
        if (lane == 0) sm[w] = s;
        __syncthreads();
        if (t == 0) ws[blk] = sm[0] + sm[1] + sm[2] + sm[3];
        __syncthreads();
        if (lane == 0) sm[w] = sq;
        __syncthreads();
        if (t == 0) ws[296 + blk] = sm[0] + sm[1] + sm[2] + sm[3];
    } else {
        const int o = blk - D_N;
        float s = 0.f;
        for (int p = t; p < P_N; p += 256) s += W[(long)o * P_N + p];
        #pragma unroll
        for (int off = 32; off; off >>= 1) s += __shfl_xor(s, off);
        if (lane == 0) sm[w] = s;
        __syncthreads();
        if (t == 0) ws[40 + o] = sm[0] + sm[1] + sm[2] + sm[3];
    }
}

// 256 rows/block. Coalesced float4 staging of x into LDS (pad 41 -> odd
// stride -> only free 2-way bank aliasing on compute reads), then thread t
// computes dist for row t from LDS. Avoids the 160 KB/CU L1-thrash of the
// strided thread-per-row global pattern.
__global__ __launch_bounds__(256) void dist_kernel(const float* __restrict__ x,
                                                   const float* __restrict__ ws,
                                                   float* __restrict__ dist) {
    __shared__ float sx[256 * 41];  // 41 KB
    const int t = threadIdx.x;
    const long rbase = (long)blockIdx.x * 256;
    const float4* __restrict__ xg = reinterpret_cast<const float4*>(x + rbase * D_N);
    #pragma unroll
    for (int k = 0; k < 10; ++k) {
        const int g = t + 256 * k;      // 2560 float4s, unit-stride across block
        const float4 v = xg[g];
        const int r = g / 10;           // each float4 lies within one row (40%4==0)
        const int c = g - r * 10;
        float* p = &sx[r * 41 + c * 4];
        p[0] = v.x; p[1] = v.y; p[2] = v.z; p[3] = v.w;
    }
    __syncthreads();
    const float* __restrict__ ps = ws;        // proto_sum (uniform -> s_load)
    const float* __restrict__ pq = ws + 296;  // per-dim proto sq
    const float* row = &sx[t * 41];
    float sumsq = 0.f, dot = 0.f, psq = 0.f;
    #pragma unroll
    for (int k = 0; k < D_N; ++k) {
        const float v = row[k];
        sumsq = fmaf(v, v, sumsq);
        dot   = fmaf(v, ps[k], dot);
        psq  += pq[k];
    }
    dist[rbase + t] = sqrtf(fmaf(512.f, sumsq, fmaf(-2.f, dot, psq)));
}

// Fill-shaped streamer: one float4 store per thread, maximal grid, no LDS.
// row index is wave-uniform (wave spans 64 consecutive j, shifts >= 6), so
// dist[row] is forced to a scalar s_load via readfirstlane -> the VMEM pipe
// issues ONLY the store, matching the rocclr fill kernel's structure.
__global__ __launch_bounds__(256) void fill_kernel(const float* __restrict__ b,
                                                   const float* __restrict__ ws,
                                                   const float* __restrict__ dist,
                                                   f4* __restrict__ xm,
                                                   f4* __restrict__ om) {
    const int t = threadIdx.x;
    const unsigned bid = blockIdx.x;
    if (bid < (unsigned)XM_BLKS) {
        const unsigned j = bid * 256u + t;              // float4 index in xmat
        const int row = __builtin_amdgcn_readfirstlane((int)(j >> 7));
        const float d = dist[row];                      // scalar load
        f4 v = {d, d, d, d};
        xm[j] = v;
    } else {
        const unsigned j = (bid - XM_BLKS) * 256u + t;  // float4 index in out
        const int row = __builtin_amdgcn_readfirstlane((int)(j >> 6));
        const float d = dist[row];                      // scalar load
        const float4 wv = reinterpret_cast<const float4*>(ws + 40)[t & 63];
        const float4 bv = reinterpret_cast<const float4*>(b)[t & 63];
        f4 v = {fmaf(d, wv.x, bv.x), fmaf(d, wv.y, bv.y),
                fmaf(d, wv.z, bv.z), fmaf(d, wv.w, bv.w)};
        om[j] = v;
    }
}

// fallback: fused single-pass (used only if ws too small for dist array)
__global__ __launch_bounds__(256) void fused_kernel(const float* __restrict__ x,
                                                    const float* __restrict__ b,
                                                    const float* __restrict__ ws,
                                                    float* __restrict__ xmat,
                                                    float* __restrict__ outp) {
    __shared__ float sdist[256];
    const int t = threadIdx.x;
    const long base = (long)blockIdx.x * 256;
    const float4* __restrict__ xr  = reinterpret_cast<const float4*>(x + (base + t) * D_N);
    const float4* __restrict__ ps4 = reinterpret_cast<const float4*>(ws);
    const float4* __restrict__ pq4 = reinterpret_cast<const float4*>(ws + 296);
    float sumsq = 0.f, dot = 0.f, psq = 0.f;
    #pragma unroll
    for (int k = 0; k < D_N / 4; ++k) {
        const float4 v = xr[k];
        const float4 p = ps4[k];
        const float4 q = pq4[k];
        sumsq = fmaf(v.x, v.x, fmaf(v.y, v.y, fmaf(v.z, v.z, fmaf(v.w, v.w, sumsq))));
        dot   = fmaf(v.x, p.x, fmaf(v.y, p.y, fmaf(v.z, p.z, fmaf(v.w, p.w, dot))));
        psq  += q.x + q.y + q.z + q.w;
    }
    sdist[t] = sqrtf(fmaf(512.f, sumsq, fmaf(-2.f, dot, psq)));
    __syncthreads();

    float4* __restrict__ xm = reinterpret_cast<float4*>(xmat + base * P_N);
    #pragma unroll 8
    for (int i = 0; i < 128; ++i) {
        const int j = i * 256 + t;
        const float d = sdist[j >> 7];
        xm[j] = make_float4(d, d, d, d);
    }
    const float4 wv = reinterpret_cast<const float4*>(ws + 40)[t & 63];
    const float4 bv = reinterpret_cast<const float4*>(b)[t & 63];
    float4* __restrict__ om = reinterpret_cast<float4*>(outp + base * O_N);
    #pragma unroll 8
    for (int i = 0; i < 64; ++i) {
        const int j = i * 256 + t;
        const float d = sdist[j >> 6];
        om[j] = make_float4(fmaf(d, wv.x, bv.x), fmaf(d, wv.y, bv.y),
                            fmaf(d, wv.z, bv.z), fmaf(d, wv.w, bv.w));
    }
}

extern "C" void kernel_launch(void* const* d_in, const int* in_sizes, int n_in,
                              void* d_out, int out_size, void* d_ws, size_t ws_size,
                              hipStream_t stream) {
    const float* inp   = (const float*)d_in[0];
    const float* proto = (const float*)d_in[1];
    const float* W     = (const float*)d_in[2];
    const float* b     = (const float*)d_in[3];
    float* ws   = (float*)d_ws;
    float* xmat = (float*)d_out;
    float* outp = xmat + (long)B_ROWS * P_N;

    hipLaunchKernelGGL(pre_kernel, dim3(296), dim3(256), 0, stream, proto, W, ws);

    if (ws_size >= (size_t)(512 + B_ROWS + 64) * sizeof(float)) {
        float* dist = ws + 512;
        hipLaunchKernelGGL(dist_kernel, dim3(B_ROWS / 256), dim3(256), 0, stream,
                           inp, ws, dist);
        hipLaunchKernelGGL(fill_kernel, dim3(XM_BLKS + OM_BLKS), dim3(256), 0, stream,
                           b, ws, dist, (f4*)xmat, (f4*)outp);
    } else {
        hipLaunchKernelGGL(fused_kernel, dim3(B_ROWS / 256), dim3(256), 0, stream,
                           inp, b, ws, xmat, outp);
    }
}

// Round 8
// 134.915 us; speedup vs baseline: 1.4646x; 1.1107x over previous
//
#include <hip/hip_runtime.h>

// PrototypeClassifier: B=262144, P=512, D=40, O=256
// xmat[i,p] = dist[i] (scalar broadcast), out[i,o] = dist[i]*Wsum[o] + b[o]
// dist[i] = sqrt(512*||x_i||^2 - 2*x_i.proto_sum + ||proto||_F^2)

#define B_ROWS 262144
#define P_N 512
#define D_N 40
#define O_N 256
#define XM_F4 (B_ROWS * P_N / 4)   // 33,554,432 float4
#define XM_BLKS (XM_F4 / 256)      // 131,072 blocks
#define OM_F4 (B_ROWS * O_N / 4)   // 16,777,216 float4
#define OM_BLKS (OM_F4 / 256)      // 65,536 blocks

typedef float f4 __attribute__((ext_vector_type(4)));

// ws layout (floats): [0,40) proto_sum, [40,296) Wsum, [296,336) per-dim proto
// sum-of-squares, [512, 512+B) dist (split path only)

__global__ __launch_bounds__(256) void pre_kernel(const float* __restrict__ proto,
                                                  const float* __restrict__ W,
                                                  float* __restrict__ ws) {
    __shared__ float sm[4];
    const int t = threadIdx.x;
    const int blk = blockIdx.x;
    const int lane = t & 63, w = t >> 6;
    if (blk < D_N) {
        float s = 0.f, sq = 0.f;
        for (int p = t; p < P_N; p += 256) {
            float v = proto[p * D_N + blk];
            s += v;
            sq += v * v;
        }
        #pragma unroll
        for (int off = 32; off; off >>= 1) {
            s += __shfl_xor(s, off);
            sq += __shfl_xor(sq, off);
        }
        if (lane == 0) sm[w] = s;
        __syncthreads();
        if (t == 0) ws[blk] = sm[0] + sm[1] + sm[2] + sm[3];
        __syncthreads();
        if (lane == 0) sm[w] = sq;
        __syncthreads();
        if (t == 0) ws[296 + blk] = sm[0] + sm[1] + sm[2] + sm[3];
    } else {
        const int o = blk - D_N;
        float s = 0.f;
        for (int p = t; p < P_N; p += 256) s += W[(long)o * P_N + p];
        #pragma unroll
        for (int off = 32; off; off >>= 1) s += __shfl_xor(s, off);
        if (lane == 0) sm[w] = s;
        __syncthreads();
        if (t == 0) ws[40 + o] = sm[0] + sm[1] + sm[2] + sm[3];
    }
}

// 256 rows/block. Coalesced float4 staging of x into LDS (pad 41 -> odd
// stride -> only free 2-way bank aliasing on compute reads), then thread t
// computes dist for row t from LDS.
__global__ __launch_bounds__(256) void dist_kernel(const float* __restrict__ x,
                                                   const float* __restrict__ ws,
                                                   float* __restrict__ dist) {
    __shared__ float sx[256 * 41];  // 41 KB
    const int t = threadIdx.x;
    const long rbase = (long)blockIdx.x * 256;
    const float4* __restrict__ xg = reinterpret_cast<const float4*>(x + rbase * D_N);
    #pragma unroll
    for (int k = 0; k < 10; ++k) {
        const int g = t + 256 * k;      // 2560 float4s, unit-stride across block
        const float4 v = xg[g];
        const int r = g / 10;           // each float4 lies within one row (40%4==0)
        const int c = g - r * 10;
        float* p = &sx[r * 41 + c * 4];
        p[0] = v.x; p[1] = v.y; p[2] = v.z; p[3] = v.w;
    }
    __syncthreads();
    const float* __restrict__ ps = ws;        // proto_sum (uniform -> s_load)
    const float* __restrict__ pq = ws + 296;  // per-dim proto sq
    const float* row = &sx[t * 41];
    float sumsq = 0.f, dot = 0.f, psq = 0.f;
    #pragma unroll
    for (int k = 0; k < D_N; ++k) {
        const float v = row[k];
        sumsq = fmaf(v, v, sumsq);
        dot   = fmaf(v, ps[k], dot);
        psq  += pq[k];
    }
    dist[rbase + t] = sqrtf(fmaf(512.f, sumsq, fmaf(-2.f, dot, psq)));
}

// Fill-shaped streamer: one float4 NONTEMPORAL store per thread, maximal grid.
// row index is wave-uniform, so dist[row] is a scalar s_load (readfirstlane).
// nt stores keep the hot read set (dist 1 MB, wv/bv 1 KB) L2-resident instead
// of being evicted by 805 MB of write-allocate traffic.
__global__ __launch_bounds__(256) void fill_kernel(const float* __restrict__ b,
                                                   const float* __restrict__ ws,
                                                   const float* __restrict__ dist,
                                                   f4* __restrict__ xm,
                                                   f4* __restrict__ om) {
    const int t = threadIdx.x;
    const unsigned bid = blockIdx.x;
    if (bid < (unsigned)XM_BLKS) {
        const unsigned j = bid * 256u + t;              // float4 index in xmat
        const int row = __builtin_amdgcn_readfirstlane((int)(j >> 7));
        const float d = dist[row];                      // scalar load
        f4 v = {d, d, d, d};
        __builtin_nontemporal_store(v, &xm[j]);
    } else {
        const unsigned j = (bid - XM_BLKS) * 256u + t;  // float4 index in out
        const int row = __builtin_amdgcn_readfirstlane((int)(j >> 6));
        const float d = dist[row];                      // scalar load
        const float4 wv = reinterpret_cast<const float4*>(ws + 40)[t & 63];
        const float4 bv = reinterpret_cast<const float4*>(b)[t & 63];
        f4 v = {fmaf(d, wv.x, bv.x), fmaf(d, wv.y, bv.y),
                fmaf(d, wv.z, bv.z), fmaf(d, wv.w, bv.w)};
        __builtin_nontemporal_store(v, &om[j]);
    }
}

// fallback: fused single-pass (used only if ws too small for dist array)
__global__ __launch_bounds__(256) void fused_kernel(const float* __restrict__ x,
                                                    const float* __restrict__ b,
                                                    const float* __restrict__ ws,
                                                    float* __restrict__ xmat,
                                                    float* __restrict__ outp) {
    __shared__ float sdist[256];
    const int t = threadIdx.x;
    const long base = (long)blockIdx.x * 256;
    const float4* __restrict__ xr  = reinterpret_cast<const float4*>(x + (base + t) * D_N);
    const float4* __restrict__ ps4 = reinterpret_cast<const float4*>(ws);
    const float4* __restrict__ pq4 = reinterpret_cast<const float4*>(ws + 296);
    float sumsq = 0.f, dot = 0.f, psq = 0.f;
    #pragma unroll
    for (int k = 0; k < D_N / 4; ++k) {
        const float4 v = xr[k];
        const float4 p = ps4[k];
        const float4 q = pq4[k];
        sumsq = fmaf(v.x, v.x, fmaf(v.y, v.y, fmaf(v.z, v.z, fmaf(v.w, v.w, sumsq))));
        dot   = fmaf(v.x, p.x, fmaf(v.y, p.y, fmaf(v.z, p.z, fmaf(v.w, p.w, dot))));
        psq  += q.x + q.y + q.z + q.w;
    }
    sdist[t] = sqrtf(fmaf(512.f, sumsq, fmaf(-2.f, dot, psq)));
    __syncthreads();

    float4* __restrict__ xm = reinterpret_cast<float4*>(xmat + base * P_N);
    #pragma unroll 8
    for (int i = 0; i < 128; ++i) {
        const int j = i * 256 + t;
        const float d = sdist[j >> 7];
        xm[j] = make_float4(d, d, d, d);
    }
    const float4 wv = reinterpret_cast<const float4*>(ws + 40)[t & 63];
    const float4 bv = reinterpret_cast<const float4*>(b)[t & 63];
    float4* __restrict__ om = reinterpret_cast<float4*>(outp + base * O_N);
    #pragma unroll 8
    for (int i = 0; i < 64; ++i) {
        const int j = i * 256 + t;
        const float d = sdist[j >> 6];
        om[j] = make_float4(fmaf(d, wv.x, bv.x), fmaf(d, wv.y, bv.y),
                            fmaf(d, wv.z, bv.z), fmaf(d, wv.w, bv.w));
    }
}

extern "C" void kernel_launch(void* const* d_in, const int* in_sizes, int n_in,
                              void* d_out, int out_size, void* d_ws, size_t ws_size,
                              hipStream_t stream) {
    const float* inp   = (const float*)d_in[0];
    const float* proto = (const float*)d_in[1];
    const float* W     = (const float*)d_in[2];
    const float* b     = (const float*)d_in[3];
    float* ws   = (float*)d_ws;
    float* xmat = (float*)d_out;
    float* outp = xmat + (long)B_ROWS * P_N;

    hipLaunchKernelGGL(pre_kernel, dim3(296), dim3(256), 0, stream, proto, W, ws);

    if (ws_size >= (size_t)(512 + B_ROWS + 64) * sizeof(float)) {
        float* dist = ws + 512;
        hipLaunchKernelGGL(dist_kernel, dim3(B_ROWS / 256), dim3(256), 0, stream,
                           inp, ws, dist);
        hipLaunchKernelGGL(fill_kernel, dim3(XM_BLKS + OM_BLKS), dim3(256), 0, stream,
                           b, ws, dist, (f4*)xmat, (f4*)outp);
    } else {
        hipLaunchKernelGGL(fused_kernel, dim3(B_ROWS / 256), dim3(256), 0, stream,
                           inp, b, ws, xmat, outp);
    }
}